// Round 17
// baseline (289.777 us; speedup 1.0000x reference)
//
#include <hip/hip_runtime.h>
#include <hip/hip_bf16.h>

// PolicyNet, fp16 MFMA:
//   A -> Af fp16, ab2[m] = A[m]·b2;  Q -> Qf fp16
//   c    = b1 + W1[:, :D] @ hist                  (fp32)
//   QWt  = (f16)(W1[:, D:] @ Q^T)  via split-K fp32 gemm + combine
//   W2   -> transpose+PACK -> W2p fragment-major [rowblk16][kblk32][lane][8]
//   s_attn_sk: Sp[kz] = Af@Qf^T over K-half (256 blocks) ; softmax_at -> at f16
//   h_kernel: H = relu(at @ QWt + c), LDS-restaged coalesced writes
//   fused_g (256x256, wave grid 4m x 2n, A in LDS 4x16KB, B direct
//            global->reg from W2p, dbuf, launch_bounds(512,1) -> no spill):
//            G = Af @ W2p; epilogue dot with H -> partial[16][16384]
//   semantic = sum partial + ab2 -> softmax over M -> out

typedef _Float16 f16;
typedef __attribute__((ext_vector_type(8))) _Float16 half8;
typedef __attribute__((ext_vector_type(4))) _Float16 half4_t;
typedef __attribute__((ext_vector_type(4))) float f32x4;

#define GLL(gp, lp)                                                              \
  __builtin_amdgcn_global_load_lds(                                              \
      (const __attribute__((address_space(1))) void*)(gp),                       \
      (__attribute__((address_space(3))) void*)(lp), 16, 0, 0)

#define WAITN(n)                                                                 \
  do {                                                                           \
    asm volatile("s_waitcnt vmcnt(" #n ")" ::: "memory");                        \
    __builtin_amdgcn_sched_barrier(0);                                           \
  } while (0)

#define MFMA16(a, b, c) __builtin_amdgcn_mfma_f32_16x16x32_f16(a, b, c, 0, 0, 0)

// ---------------- 4-wave 128x128 fp16 K-loop, depth-3 ----------------
// BK=32. LDS: 4 sets x {A 8KB, B 8KB} = 64KB. vmcnt(12) steady.
template <int NT, int LDA, int LDB>
__device__ __forceinline__ void kloop1(const f16* __restrict__ A,
                                       const f16* __restrict__ B,
                                       f16* __restrict__ SM,
                                       f32x4 (&acc)[4][4],
                                       int lane, int wv, int wm, int wn) {
  static_assert(NT >= 4, "depth-3 pipeline needs NT >= 4");
  const int f = lane & 15, kk = lane >> 4;
  const int cS = (lane & 7) ^ (lane >> 3);
  const int kkS = (cS & 3) * 8;
  const int rS = 2 * (lane >> 3) + (cS >> 2);
  const size_t offA0 = (size_t)(16 * (wv * 2 + 0) + rS) * LDA + kkS;
  const size_t offA1 = (size_t)(16 * (wv * 2 + 1) + rS) * LDA + kkS;
  const size_t offB0 = (size_t)(16 * (wv * 2 + 0) + rS) * LDB + kkS;
  const size_t offB1 = (size_t)(16 * (wv * 2 + 1) + rS) * LDB + kkS;
  const int Ld0 = (wv * 2 + 0) * 512, Ld1 = (wv * 2 + 1) * 512;

  int aoff[4], boff[4];
  #pragma unroll
  for (int mf = 0; mf < 4; ++mf) {
    const int R = wm + mf * 16 + f;
    const int c2 = (((R & 1) << 2) | kk) ^ ((R >> 1) & 7);
    aoff[mf] = (R >> 1) * 64 + c2 * 8;
  }
  #pragma unroll
  for (int nf = 0; nf < 4; ++nf) {
    const int R = wn + nf * 16 + f;
    const int c2 = (((R & 1) << 2) | kk) ^ ((R >> 1) & 7);
    boff[nf] = (R >> 1) * 64 + c2 * 8;
  }

  auto STAGE = [&](int set, int kt) {
    f16* base = SM + set * 8192;
    GLL(A + offA0 + kt, base + Ld0);
    GLL(A + offA1 + kt, base + Ld1);
    GLL(B + offB0 + kt, base + 4096 + Ld0);
    GLL(B + offB1 + kt, base + 4096 + Ld1);
  };
  auto COMPUTE = [&](int set) {
    const f16* p = SM + set * 8192;
    half8 a[4], b[4];
    #pragma unroll
    for (int mf = 0; mf < 4; ++mf) a[mf] = *(const half8*)&p[aoff[mf]];
    #pragma unroll
    for (int nf = 0; nf < 4; ++nf) b[nf] = *(const half8*)&p[4096 + boff[nf]];
    __builtin_amdgcn_s_setprio(1);
    #pragma unroll
    for (int mf = 0; mf < 4; ++mf)
      #pragma unroll
      for (int nf = 0; nf < 4; ++nf)
        acc[mf][nf] = MFMA16(a[mf], b[nf], acc[mf][nf]);
    __builtin_amdgcn_s_setprio(0);
  };

  STAGE(0, 0);
  STAGE(1, 32);
  STAGE(2, 64);
  #pragma unroll 1
  for (int t = 0; t < NT - 3; ++t) {
    STAGE((t + 3) & 3, (t + 3) * 32);
    WAITN(12);
    __builtin_amdgcn_s_barrier();
    COMPUTE(t & 3);
    __builtin_amdgcn_s_barrier();
  }
  WAITN(8);
  __builtin_amdgcn_s_barrier();
  COMPUTE((NT - 3) & 3);
  __builtin_amdgcn_s_barrier();
  WAITN(4);
  __builtin_amdgcn_s_barrier();
  COMPUTE((NT - 2) & 3);
  __builtin_amdgcn_s_barrier();
  WAITN(0);
  __builtin_amdgcn_s_barrier();
  COMPUTE((NT - 1) & 3);
  __builtin_amdgcn_s_barrier();
}

// ---------------- prep kernels ----------------

__global__ __launch_bounds__(256) void c_kernel(const float* __restrict__ W1,
                                                const float* __restrict__ b1,
                                                const float* __restrict__ hist,
                                                float* __restrict__ c) {
  const int wave = threadIdx.x >> 6, lane = threadIdx.x & 63;
  const int j = blockIdx.x * 4 + wave;
  const float* row = W1 + (size_t)j * 4096;
  float s = 0.f;
  #pragma unroll 2
  for (int kq = lane; kq < 512; kq += 64) {
    const float4 w = *(const float4*)&row[kq * 4];
    const float4 h = *(const float4*)&hist[kq * 4];
    s += w.x * h.x + w.y * h.y + w.z * h.z + w.w * h.w;
  }
  #pragma unroll
  for (int mask = 1; mask < 64; mask <<= 1) s += __shfl_xor(s, mask);
  if (lane == 0) c[j] = s + b1[j];
}

__device__ __forceinline__ half4_t f16hi4(const float4 v) {
  half4_t h;
  h.x = (f16)v.x; h.y = (f16)v.y; h.z = (f16)v.z; h.w = (f16)v.w;
  return h;
}

// blocks 0..4095: A rows (4/block) -> Af + ab2;  blocks 4096..4127: Q -> Qf
__global__ __launch_bounds__(256) void prep_AQ(const float* __restrict__ A,
                                               const float* __restrict__ Q,
                                               const float* __restrict__ b2,
                                               f16* __restrict__ Af,
                                               f16* __restrict__ Qf,
                                               float* __restrict__ ab2) {
  const int wv = threadIdx.x >> 6, lane = threadIdx.x & 63;
  if (blockIdx.x < 4096) {
    const size_t row = (size_t)blockIdx.x * 4 + wv;
    const float* ar = A + row * 2048;
    float dot = 0.f;
    #pragma unroll 2
    for (int c0 = 0; c0 < 2048; c0 += 256) {
      const int col = c0 + lane * 4;
      const float4 v = *(const float4*)&ar[col];
      const float4 bb = *(const float4*)&b2[col];
      dot += v.x * bb.x + v.y * bb.y + v.z * bb.z + v.w * bb.w;
      *(half4_t*)&Af[row * 2048 + col] = f16hi4(v);
    }
    #pragma unroll
    for (int mask = 1; mask < 64; mask <<= 1) dot += __shfl_xor(dot, mask);
    if (lane == 0) ab2[row] = dot;
  } else {
    const size_t row = (size_t)(blockIdx.x - 4096) * 4 + wv;
    const float* qr = Q + row * 2048;
    #pragma unroll 2
    for (int c0 = 0; c0 < 2048; c0 += 256) {
      const int col = c0 + lane * 4;
      const float4 v = *(const float4*)&qr[col];
      *(half4_t*)&Qf[row * 2048 + col] = f16hi4(v);
    }
  }
}

// W2 [2048][2048] -> W2p packed fragment-major:
// element (j,k) -> [rb=j>>4][kb=k>>5][lane=((k&31)>>3)*16 + (j&15)][e=k&7]
__global__ __launch_bounds__(256) void transpose_pack(const float* __restrict__ src,
                                                      f16* __restrict__ W2p) {
  __shared__ float T[64][65];
  const int c0 = blockIdx.x * 64, r0 = blockIdx.y * 64;   // c=j, r=k
  const int t = threadIdx.x;
  {
    const int rl = t >> 4, cl = (t & 15) * 4;
    #pragma unroll
    for (int ii = 0; ii < 4; ++ii) {
      const float4 v = *(const float4*)&src[(size_t)(r0 + rl + ii * 16) * 2048 + c0 + cl];
      T[rl + ii * 16][cl + 0] = v.x; T[rl + ii * 16][cl + 1] = v.y;
      T[rl + ii * 16][cl + 2] = v.z; T[rl + ii * 16][cl + 3] = v.w;
    }
  }
  __syncthreads();
  const int cc = t >> 2, rr0 = (t & 3) * 16;
  f16 u[16];
  #pragma unroll
  for (int k = 0; k < 16; ++k) u[k] = (f16)T[rr0 + k][cc];
  const int j = c0 + cc;
  const int k0 = r0 + rr0;           // multiple of 16
  const int rb = j >> 4, f = j & 15;
  const int kb = k0 >> 5, kk0 = (k0 & 31) >> 3;   // 0 or 2
  f16* p0 = W2p + ((size_t)(rb * 64 + kb) * 64 + kk0 * 16 + f) * 8;
  f16* p1 = W2p + ((size_t)(rb * 64 + kb) * 64 + (kk0 + 1) * 16 + f) * 8;
  *(half4_t*)&p0[0] = *(half4_t*)&u[0];
  *(half4_t*)&p0[4] = *(half4_t*)&u[4];
  *(half4_t*)&p1[0] = *(half4_t*)&u[8];
  *(half4_t*)&p1[4] = *(half4_t*)&u[12];
}

// fp32 tiled GEMM (B^T layout), split-K fp32 partial output
template <int BM, int TM>
__global__ __launch_bounds__(256) void gemm_bt_sk(const float* __restrict__ A,
                                                  const float* __restrict__ B,
                                                  float* __restrict__ Cpart,
                                                  int Kslab, int lda, int ldb,
                                                  int ldc, int M) {
  constexpr int BN = 64, BK = 32;
  constexpr int ASTR = BM + 12, BSTR = BN + 4;
  __shared__ float As[BK][ASTR];
  __shared__ float Bs[BK][BSTR];
  const int tid = threadIdx.x;
  const int tx = tid & 15, ty = tid >> 4;
  const int m0 = ty * TM, n0 = tx * 4;
  const size_t bm = (size_t)blockIdx.x * BM, bn = (size_t)blockIdx.y * BN;
  const int kb = blockIdx.z * Kslab;
  const float* Ab = A + bm * lda;
  const float* Bb = B + bn * ldb;
  float acc[TM][4];
  #pragma unroll
  for (int i = 0; i < TM; ++i)
    #pragma unroll
    for (int j = 0; j < 4; ++j) acc[i][j] = 0.f;
  for (int kt = kb; kt < kb + Kslab; kt += BK) {
    #pragma unroll
    for (int it = 0; it < BM * BK / 4 / 256; ++it) {
      const int idx = it * 256 + tid;
      const int row = idx >> 3, kq = idx & 7;
      const float4 v = *(const float4*)&Ab[(size_t)row * lda + kt + kq * 4];
      As[kq * 4 + 0][row] = v.x; As[kq * 4 + 1][row] = v.y;
      As[kq * 4 + 2][row] = v.z; As[kq * 4 + 3][row] = v.w;
    }
    #pragma unroll
    for (int it = 0; it < BN * BK / 4 / 256; ++it) {
      const int idx = it * 256 + tid;
      const int row = idx >> 3, kq = idx & 7;
      const float4 v = *(const float4*)&Bb[(size_t)row * ldb + kt + kq * 4];
      Bs[kq * 4 + 0][row] = v.x; Bs[kq * 4 + 1][row] = v.y;
      Bs[kq * 4 + 2][row] = v.z; Bs[kq * 4 + 3][row] = v.w;
    }
    __syncthreads();
    #pragma unroll
    for (int k = 0; k < BK; ++k) {
      float av[TM];
      #pragma unroll
      for (int i = 0; i < TM; ++i) av[i] = As[k][m0 + i];
      const float4 b = *(const float4*)&Bs[k][n0];
      const float bv[4] = {b.x, b.y, b.z, b.w};
      #pragma unroll
      for (int i = 0; i < TM; ++i)
        #pragma unroll
        for (int j = 0; j < 4; ++j) acc[i][j] = fmaf(av[i], bv[j], acc[i][j]);
    }
    __syncthreads();
  }
  float* base = Cpart + (size_t)blockIdx.z * M * ldc;
  #pragma unroll
  for (int i = 0; i < TM; ++i) {
    float* crow = base + (bm + m0 + i) * (size_t)ldc + bn + n0;
    #pragma unroll
    for (int j = 0; j < 4; ++j) crow[j] = acc[i][j];
  }
}

// QWt[i] = (f16) sum_z part[z][i]
__global__ __launch_bounds__(256) void qwt_combine(const float* __restrict__ part,
                                                   f16* __restrict__ QWt) {
  const size_t i = ((size_t)blockIdx.x * 256 + threadIdx.x) * 4;
  float4 s = make_float4(0.f, 0.f, 0.f, 0.f);
  #pragma unroll
  for (int z = 0; z < 8; ++z) {
    const float4 v = *(const float4*)&part[(size_t)z * 262144 + i];
    s.x += v.x; s.y += v.y; s.z += v.z; s.w += v.w;
  }
  *(half4_t*)&QWt[i] = f16hi4(s);
}

// ------- S partials: Sp[kz][m][n] = Af[m, kz*1024:+1024] @ Qf^T -------
__global__ __launch_bounds__(256, 2) void s_attn_sk(const f16* __restrict__ Af,
                                                    const f16* __restrict__ Qf,
                                                    float* __restrict__ Sp) {
  __shared__ f16 SM[32768];  // 64 KB
  const int tid = threadIdx.x, lane = tid & 63, wv = tid >> 6;
  const int wm = (wv >> 1) * 64, wn = (wv & 1) * 64;
  const int f = lane & 15, kk = lane >> 4;
  const size_t bm = (size_t)(blockIdx.x >> 1) * 128;
  const int kz = blockIdx.x & 1;

  f32x4 acc[4][4];
  #pragma unroll
  for (int mf = 0; mf < 4; ++mf)
    #pragma unroll
    for (int nf = 0; nf < 4; ++nf) acc[mf][nf] = 0.f;

  kloop1<32, 2048, 2048>(Af + bm * 2048 + kz * 1024, Qf + kz * 1024,
                         SM, acc, lane, wv, wm, wn);

  float* out = Sp + (size_t)kz * 16384 * 128;
  #pragma unroll
  for (int mf = 0; mf < 4; ++mf)
    #pragma unroll
    for (int r = 0; r < 4; ++r) {
      const size_t row = bm + wm + mf * 16 + kk * 4 + r;
      #pragma unroll
      for (int nf = 0; nf < 4; ++nf)
        out[row * 128 + wn + nf * 16 + f] = acc[mf][nf][r];
    }
}

// at = (f16) softmax_rows(Sp0 + Sp1).  grid 512 x 256 (8 threads/row).
__global__ __launch_bounds__(256) void softmax_at(const float* __restrict__ Sp,
                                                  f16* __restrict__ at) {
  const int tid = threadIdx.x;
  const int sub = tid & 7;
  const size_t row = (size_t)blockIdx.x * 32 + (tid >> 3);
  const float* p0 = Sp + row * 128 + sub * 16;
  const float* p1 = p0 + (size_t)16384 * 128;
  float v[16];
  #pragma unroll
  for (int q = 0; q < 4; ++q) {
    const float4 a = ((const float4*)p0)[q];
    const float4 b = ((const float4*)p1)[q];
    v[q * 4 + 0] = a.x + b.x; v[q * 4 + 1] = a.y + b.y;
    v[q * 4 + 2] = a.z + b.z; v[q * 4 + 3] = a.w + b.w;
  }
  float mx = v[0];
  #pragma unroll
  for (int e = 1; e < 16; ++e) mx = fmaxf(mx, v[e]);
  mx = fmaxf(mx, __shfl_xor(mx, 1));
  mx = fmaxf(mx, __shfl_xor(mx, 2));
  mx = fmaxf(mx, __shfl_xor(mx, 4));
  float sm = 0.f;
  #pragma unroll
  for (int e = 0; e < 16; ++e) { v[e] = __expf(v[e] - mx); sm += v[e]; }
  sm += __shfl_xor(sm, 1);
  sm += __shfl_xor(sm, 2);
  sm += __shfl_xor(sm, 4);
  const float inv = 1.0f / sm;
  f16* po = at + row * 128 + sub * 16;
  #pragma unroll
  for (int q = 0; q < 4; ++q) {
    half4_t h;
    h.x = (f16)(v[q * 4 + 0] * inv); h.y = (f16)(v[q * 4 + 1] * inv);
    h.z = (f16)(v[q * 4 + 2] * inv); h.w = (f16)(v[q * 4 + 3] * inv);
    *(half4_t*)&po[q * 4] = h;
  }
}

// ---------------- H = relu(at @ QWt + c), 128x128 tile, K=128 ----------------
__global__ __launch_bounds__(256, 2) void h_kernel(const f16* __restrict__ at,
                                                   const f16* __restrict__ QWt,
                                                   const float* __restrict__ cvec,
                                                   f16* __restrict__ H) {
  __shared__ f16 SM[32768];  // 64 KB
  const int tid = threadIdx.x, lane = tid & 63, wv = tid >> 6;
  const int wm = (wv >> 1) * 64, wn = (wv & 1) * 64;
  const int f = lane & 15, kk = lane >> 4;
  const size_t bm = (size_t)(blockIdx.x & 127) * 128;
  const size_t bn = (size_t)(blockIdx.x >> 7) * 128;

  f32x4 acc[4][4];
  #pragma unroll
  for (int mf = 0; mf < 4; ++mf)
    #pragma unroll
    for (int nf = 0; nf < 4; ++nf) acc[mf][nf] = 0.f;

  kloop1<4, 128, 128>(at + bm * 128, QWt + bn * 128, SM, acc, lane, wv, wm, wn);

  float ccv[4];
  #pragma unroll
  for (int nf = 0; nf < 4; ++nf) ccv[nf] = cvec[bn + wn + nf * 16 + f];

  __syncthreads();
  constexpr int STR = 136;
  f16* T = SM;
  #pragma unroll
  for (int mf = 0; mf < 4; ++mf)
    #pragma unroll
    for (int r = 0; r < 4; ++r) {
      const int row = wm + mf * 16 + kk * 4 + r;
      #pragma unroll
      for (int nf = 0; nf < 4; ++nf)
        T[row * STR + wn + nf * 16 + f] =
            (f16)fmaxf(acc[mf][nf][r] + ccv[nf], 0.f);
    }
  __syncthreads();
  #pragma unroll
  for (int it = 0; it < 8; ++it) {
    const int row = it * 16 + (tid >> 4);
    const int ch = tid & 15;
    const float4 vv = *(const float4*)&T[row * STR + ch * 8];
    *(float4*)&H[(bm + row) * 2048 + bn + ch * 8] = vv;
  }
}

// --- fused G: G = Af @ W2p (256x256 tile, 4m x 2n waves, B in regs) ---
__global__ __launch_bounds__(512, 1) void fused_g(
    const f16* __restrict__ Af, const f16* __restrict__ H,
    const f16* __restrict__ W2p, float* __restrict__ partial) {
  extern __shared__ f16 SM[];  // 64 KB: 4 sets x A 16KB
  const int tid = threadIdx.x, lane = tid & 63, wv = tid >> 6;   // wv 0..7
  const int wm = (wv >> 1) * 64;        // 4 m positions x 64
  const int wn = (wv & 1) * 128;        // 2 n positions x 128
  const int f = lane & 15, kk = lane >> 4;
  // bijective XCD swizzle: nwg=512, 8 XCDs, 64 per XCD
  const int lin = blockIdx.x;
  const int sid = (lin & 7) * 64 + (lin >> 3);
  const int bmI = sid & 63, bnI = sid >> 6;       // 64 m-blocks x 8 n-blocks
  const size_t bm = (size_t)bmI * 256;
  const size_t bn = (size_t)bnI * 256;
  const f16* A = Af + bm * 2048;
  const int rbase = (int)(bn >> 4) + (wn >> 4);   // packed rowblk base

  const int cS = (lane & 7) ^ (lane >> 3);
  const int kkS = (cS & 3) * 8;
  const int rS = 2 * (lane >> 3) + (cS >> 2);
  const size_t offA0 = (size_t)(16 * (wv * 2 + 0) + rS) * 2048 + kkS;
  const size_t offA1 = (size_t)(16 * (wv * 2 + 1) + rS) * 2048 + kkS;
  const int Ld0 = (wv * 2 + 0) * 512, Ld1 = (wv * 2 + 1) * 512;

  int aoff[4];
  #pragma unroll
  for (int mf = 0; mf < 4; ++mf) {
    const int R = wm + mf * 16 + f;
    const int c2 = (((R & 1) << 2) | kk) ^ ((R >> 1) & 7);
    aoff[mf] = (R >> 1) * 64 + c2 * 8;
  }

  f32x4 acc[4][8];
  #pragma unroll
  for (int mf = 0; mf < 4; ++mf)
    #pragma unroll
    for (int nf = 0; nf < 8; ++nf) acc[mf][nf] = 0.f;

  half8 bA[8], bB[8];

#define STAGE_A(set, kt)                                                         \
  do {                                                                           \
    f16* base_ = SM + (set) * 8192;                                              \
    GLL(A + offA0 + (kt), base_ + Ld0);                                          \
    GLL(A + offA1 + (kt), base_ + Ld1);                                          \
  } while (0)

#define BLOAD(dst, t)                                                            \
  do {                                                                           \
    _Pragma("unroll")                                                            \
    for (int nf = 0; nf < 8; ++nf)                                               \
      dst[nf] = *(const half8*)&W2p[((size_t)(rbase + nf) * 64 + (t)) * 512 +    \
                                    lane * 8];                                   \
  } while (0)

#define COMPUTE(set, b)                                                          \
  do {                                                                           \
    const f16* p_ = SM + (set) * 8192;                                           \
    half8 a_[4];                                                                 \
    _Pragma("unroll")                                                            \
    for (int mf = 0; mf < 4; ++mf) a_[mf] = *(const half8*)&p_[aoff[mf]];        \
    __builtin_amdgcn_s_setprio(1);                                               \
    _Pragma("unroll")                                                            \
    for (int mf = 0; mf < 4; ++mf)                                               \
      _Pragma("unroll")                                                          \
      for (int nf = 0; nf < 8; ++nf)                                             \
        acc[mf][nf] = MFMA16(a_[mf], b[nf], acc[mf][nf]);                        \
    __builtin_amdgcn_s_setprio(0);                                               \
  } while (0)

  BLOAD(bA, 0);
  STAGE_A(0, 0);
  STAGE_A(1, 32);
  #pragma unroll 1
  for (int t = 0; t < 62; t += 2) {
    BLOAD(bB, t + 1);
    STAGE_A((t + 2) & 3, (t + 2) * 32);
    WAITN(10);
    __builtin_amdgcn_s_barrier();
    COMPUTE(t & 3, bA);
    BLOAD(bA, t + 2);
    STAGE_A((t + 3) & 3, (t + 3) * 32);
    WAITN(10);
    __builtin_amdgcn_s_barrier();
    COMPUTE((t + 1) & 3, bB);
  }
  // tail: t = 62, 63
  BLOAD(bB, 63);
  WAITN(8);
  __builtin_amdgcn_s_barrier();
  COMPUTE(2, bA);
  WAITN(0);
  __builtin_amdgcn_s_barrier();
  COMPUTE(3, bB);

#undef STAGE_A
#undef BLOAD
#undef COMPUTE

  // epilogue: load H frags from global, dot over 8 n-frags, reduce 16 lanes
  #pragma unroll
  for (int mf = 0; mf < 4; ++mf)
    #pragma unroll
    for (int r = 0; r < 4; ++r) {
      const size_t hrow = (bm + wm + mf * 16 + kk * 4 + r) * 2048 + bn + wn + f;
      float s = 0.f;
      #pragma unroll
      for (int nf = 0; nf < 8; ++nf)
        s += (float)H[hrow + nf * 16] * acc[mf][nf][r];
      s += __shfl_xor(s, 1);
      s += __shfl_xor(s, 2);
      s += __shfl_xor(s, 4);
      s += __shfl_xor(s, 8);
      if (f == 0) {
        const size_t slab = (size_t)(bnI * 2 + (wv & 1)) * 16384;
        partial[slab + bm + wm + mf * 16 + kk * 4 + r] = s;
      }
    }
}

// ---------------- final reduction + softmax over M ----------------

__global__ __launch_bounds__(256) void k_sem(const float* __restrict__ partial,
                                             const float* __restrict__ ab2,
                                             float* __restrict__ semantic,
                                             float* __restrict__ bstats) {
  const int m = blockIdx.x * 256 + threadIdx.x;
  float s = ab2[m];
  #pragma unroll
  for (int nb = 0; nb < 16; ++nb) s += partial[(size_t)nb * 16384 + m];
  semantic[m] = s;
  float mx = s;
  #pragma unroll
  for (int mask = 1; mask < 64; mask <<= 1) mx = fmaxf(mx, __shfl_xor(mx, mask));
  __shared__ float wmax[4], wsum[4];
  const int wave = threadIdx.x >> 6, lane = threadIdx.x & 63;
  if (lane == 0) wmax[wave] = mx;
  __syncthreads();
  const float bmax = fmaxf(fmaxf(wmax[0], wmax[1]), fmaxf(wmax[2], wmax[3]));
  float e = expf(s - bmax);
  #pragma unroll
  for (int mask = 1; mask < 64; mask <<= 1) e += __shfl_xor(e, mask);
  if (lane == 0) wsum[wave] = e;
  __syncthreads();
  if (threadIdx.x == 0) {
    bstats[blockIdx.x * 2] = bmax;
    bstats[blockIdx.x * 2 + 1] = wsum[0] + wsum[1] + wsum[2] + wsum[3];
  }
}

__global__ __launch_bounds__(256) void k_out(const float* __restrict__ semantic,
                                             const float* __restrict__ bstats,
                                             float* __restrict__ out) {
  __shared__ float g0s, g1s;
  const int tid = threadIdx.x;
  if (tid < 64) {
    const float bm = bstats[tid * 2], bs = bstats[tid * 2 + 1];
    float gm = bm;
    #pragma unroll
    for (int mask = 1; mask < 64; mask <<= 1) gm = fmaxf(gm, __shfl_xor(gm, mask));
    float gs = bs * expf(bm - gm);
    #pragma unroll
    for (int mask = 1; mask < 64; mask <<= 1) gs += __shfl_xor(gs, mask);
    if (tid == 0) { g0s = gm; g1s = gs; }
  }
  __syncthreads();
  const int m = blockIdx.x * 256 + tid;
  out[m] = expf(semantic[m] - g0s) / g1s;
}

// ---------------- launch ----------------

extern "C" void kernel_launch(void* const* d_in, const int* in_sizes, int n_in,
                              void* d_out, int out_size, void* d_ws, size_t ws_size,
                              hipStream_t stream) {
  (void)in_sizes; (void)n_in; (void)out_size; (void)ws_size;
  const float* A    = (const float*)d_in[0];  // [16384][2048]
  const float* Q    = (const float*)d_in[1];  // [128][2048]
  const float* hist = (const float*)d_in[2];  // [2048]
  const float* W1   = (const float*)d_in[3];  // [2048][4096]
  const float* b1   = (const float*)d_in[4];  // [2048]
  const float* W2   = (const float*)d_in[5];  // [2048][2048]
  const float* b2   = (const float*)d_in[6];  // [2048]
  float* out = (float*)d_out;                 // [16384]

  char* ws = (char*)d_ws;
  f16* Af      = (f16*)ws;   ws += (size_t)16384 * 2048 * 2;  // 64 MB
  f16* Hbuf    = (f16*)ws;   ws += (size_t)16384 * 2048 * 2;  // 64 MB
  f16* W2p     = (f16*)ws;   ws += (size_t)2048 * 2048 * 2;   // 8 MB
  f16* Qf      = (f16*)ws;   ws += (size_t)128 * 2048 * 2;
  f16* QWt     = (f16*)ws;   ws += (size_t)2048 * 128 * 2;
  f16* at      = (f16*)ws;   ws += (size_t)16384 * 128 * 2;   // 4 MB
  float* qwt_part = (float*)ws; ws += (size_t)8 * 2048 * 128 * 4;  // 8 MB
  float* Sp    = (float*)ws; ws += (size_t)2 * 16384 * 128 * 4;    // 16 MB
  float* c_vec = (float*)ws; ws += 2048 * 4;
  float* ab2   = (float*)ws; ws += 16384 * 4;
  float* partial  = (float*)ws; ws += (size_t)16 * 16384 * 4; // 1 MB
  float* semantic = (float*)ws; ws += 16384 * 4;
  float* bstats   = (float*)ws; ws += 128 * 4;

  hipFuncSetAttribute((const void*)fused_g,
                      hipFuncAttributeMaxDynamicSharedMemorySize, 65536);

  // prep
  c_kernel<<<512, 256, 0, stream>>>(W1, b1, hist, c_vec);
  gemm_bt_sk<32, 2><<<dim3(64, 2, 8), 256, 0, stream>>>(W1 + 2048, Q, qwt_part,
                                                        256, 4096, 2048, 128, 2048);
  qwt_combine<<<256, 256, 0, stream>>>(qwt_part, QWt);
  transpose_pack<<<dim3(32, 32), 256, 0, stream>>>(W2, W2p);
  prep_AQ<<<4128, 256, 0, stream>>>(A, Q, b2, Af, Qf, ab2);
  // S partials (split-K 2) + softmax
  s_attn_sk<<<256, 256, 0, stream>>>(Af, Qf, Sp);
  softmax_at<<<512, 256, 0, stream>>>(Sp, at);
  // H = relu(at@QWt + c)
  h_kernel<<<2048, 256, 0, stream>>>(at, QWt, c_vec, Hbuf);
  // G = Af@W2p (B direct-to-reg, 256-VGPR budget) + dot with H
  fused_g<<<512, 512, 65536, stream>>>(Af, Hbuf, W2p, partial);
  // semantic + softmax over M
  k_sem<<<64, 256, 0, stream>>>(partial, ab2, semantic, bstats);
  k_out<<<64, 256, 0, stream>>>(semantic, bstats, out);
}

// Round 18
// 267.740 us; speedup vs baseline: 1.0823x; 1.0823x over previous
//
#include <hip/hip_runtime.h>
#include <hip/hip_bf16.h>

// PolicyNet, fp16 MFMA (R15 proven configuration):
//   A -> Af fp16, ab2[m] = A[m]·b2;  Q -> Qf fp16
//   c    = b1 + W1[:, :D] @ hist                  (fp32)
//   QWt  = (f16)(W1[:, D:] @ Q^T)  via split-K fp32 gemm + combine
//   W2   -> transpose -> W2t f16 [j][k]
//   s_attn_sk: Sp[kz] = Af@Qf^T over K-half (256 blocks, full GPU)
//   softmax_at: at = softmax_rows(Sp0+Sp1) f16
//   h_kernel: H = relu(at @ QWt + c), LDS-restaged coalesced writes
//   fused_g (256x256, 8 waves, 128KB LDS, 4-set rotation, 1 barrier/step):
//       G = Af @ W2t; epilogue dot with H
//   semantic = sum partial + ab2 -> softmax over M -> out

typedef _Float16 f16;
typedef __attribute__((ext_vector_type(8))) _Float16 half8;
typedef __attribute__((ext_vector_type(4))) _Float16 half4_t;
typedef __attribute__((ext_vector_type(4))) float f32x4;

#define GLL(gp, lp)                                                              \
  __builtin_amdgcn_global_load_lds(                                              \
      (const __attribute__((address_space(1))) void*)(gp),                       \
      (__attribute__((address_space(3))) void*)(lp), 16, 0, 0)

#define WAITN(n)                                                                 \
  do {                                                                           \
    asm volatile("s_waitcnt vmcnt(" #n ")" ::: "memory");                        \
    __builtin_amdgcn_sched_barrier(0);                                           \
  } while (0)

#define MFMA16(a, b, c) __builtin_amdgcn_mfma_f32_16x16x32_f16(a, b, c, 0, 0, 0)

// ---------------- 4-wave 128x128 fp16 K-loop, depth-3 ----------------
// BK=32. LDS: 4 sets x {A 8KB, B 8KB} = 64KB. vmcnt(12) steady.
template <int NT, int LDA, int LDB>
__device__ __forceinline__ void kloop1(const f16* __restrict__ A,
                                       const f16* __restrict__ B,
                                       f16* __restrict__ SM,
                                       f32x4 (&acc)[4][4],
                                       int lane, int wv, int wm, int wn) {
  static_assert(NT >= 4, "depth-3 pipeline needs NT >= 4");
  const int f = lane & 15, kk = lane >> 4;
  const int cS = (lane & 7) ^ (lane >> 3);
  const int kkS = (cS & 3) * 8;
  const int rS = 2 * (lane >> 3) + (cS >> 2);
  const size_t offA0 = (size_t)(16 * (wv * 2 + 0) + rS) * LDA + kkS;
  const size_t offA1 = (size_t)(16 * (wv * 2 + 1) + rS) * LDA + kkS;
  const size_t offB0 = (size_t)(16 * (wv * 2 + 0) + rS) * LDB + kkS;
  const size_t offB1 = (size_t)(16 * (wv * 2 + 1) + rS) * LDB + kkS;
  const int Ld0 = (wv * 2 + 0) * 512, Ld1 = (wv * 2 + 1) * 512;

  int aoff[4], boff[4];
  #pragma unroll
  for (int mf = 0; mf < 4; ++mf) {
    const int R = wm + mf * 16 + f;
    const int c2 = (((R & 1) << 2) | kk) ^ ((R >> 1) & 7);
    aoff[mf] = (R >> 1) * 64 + c2 * 8;
  }
  #pragma unroll
  for (int nf = 0; nf < 4; ++nf) {
    const int R = wn + nf * 16 + f;
    const int c2 = (((R & 1) << 2) | kk) ^ ((R >> 1) & 7);
    boff[nf] = (R >> 1) * 64 + c2 * 8;
  }

  auto STAGE = [&](int set, int kt) {
    f16* base = SM + set * 8192;
    GLL(A + offA0 + kt, base + Ld0);
    GLL(A + offA1 + kt, base + Ld1);
    GLL(B + offB0 + kt, base + 4096 + Ld0);
    GLL(B + offB1 + kt, base + 4096 + Ld1);
  };
  auto COMPUTE = [&](int set) {
    const f16* p = SM + set * 8192;
    half8 a[4], b[4];
    #pragma unroll
    for (int mf = 0; mf < 4; ++mf) a[mf] = *(const half8*)&p[aoff[mf]];
    #pragma unroll
    for (int nf = 0; nf < 4; ++nf) b[nf] = *(const half8*)&p[4096 + boff[nf]];
    __builtin_amdgcn_s_setprio(1);
    #pragma unroll
    for (int mf = 0; mf < 4; ++mf)
      #pragma unroll
      for (int nf = 0; nf < 4; ++nf)
        acc[mf][nf] = MFMA16(a[mf], b[nf], acc[mf][nf]);
    __builtin_amdgcn_s_setprio(0);
  };

  STAGE(0, 0);
  STAGE(1, 32);
  STAGE(2, 64);
  #pragma unroll 1
  for (int t = 0; t < NT - 3; ++t) {
    STAGE((t + 3) & 3, (t + 3) * 32);
    WAITN(12);
    __builtin_amdgcn_s_barrier();
    COMPUTE(t & 3);
    __builtin_amdgcn_s_barrier();
  }
  WAITN(8);
  __builtin_amdgcn_s_barrier();
  COMPUTE((NT - 3) & 3);
  __builtin_amdgcn_s_barrier();
  WAITN(4);
  __builtin_amdgcn_s_barrier();
  COMPUTE((NT - 2) & 3);
  __builtin_amdgcn_s_barrier();
  WAITN(0);
  __builtin_amdgcn_s_barrier();
  COMPUTE((NT - 1) & 3);
  __builtin_amdgcn_s_barrier();
}

// ---------------- 8-wave 256x256 fp16 K-loop, 4 sets, 1 barrier/step ---------
// BK=32. LDS: 4 sets x {A 16KB, B 16KB} = 128KB dynamic. depth-2, vmcnt(8).
template <int NT, int LDA, int LDB>
__device__ __forceinline__ void kloop256(const f16* __restrict__ A,
                                         const f16* __restrict__ B,
                                         f16* __restrict__ SM,
                                         f32x4 (&acc)[8][4],
                                         int lane, int wv, int wm, int wn) {
  static_assert(NT >= 3, "pipeline needs NT >= 3");
  const int f = lane & 15, kk = lane >> 4;
  const int cS = (lane & 7) ^ (lane >> 3);
  const int kkS = (cS & 3) * 8;
  const int rS = 2 * (lane >> 3) + (cS >> 2);
  const size_t offA0 = (size_t)(16 * (wv * 2 + 0) + rS) * LDA + kkS;
  const size_t offA1 = (size_t)(16 * (wv * 2 + 1) + rS) * LDA + kkS;
  const size_t offB0 = (size_t)(16 * (wv * 2 + 0) + rS) * LDB + kkS;
  const size_t offB1 = (size_t)(16 * (wv * 2 + 1) + rS) * LDB + kkS;
  const int Ld0 = (wv * 2 + 0) * 512, Ld1 = (wv * 2 + 1) * 512;

  int aoff[8], boff[4];
  #pragma unroll
  for (int mf = 0; mf < 8; ++mf) {
    const int R = wm + mf * 16 + f;
    const int c2 = (((R & 1) << 2) | kk) ^ ((R >> 1) & 7);
    aoff[mf] = (R >> 1) * 64 + c2 * 8;
  }
  #pragma unroll
  for (int nf = 0; nf < 4; ++nf) {
    const int R = wn + nf * 16 + f;
    const int c2 = (((R & 1) << 2) | kk) ^ ((R >> 1) & 7);
    boff[nf] = 8192 + (R >> 1) * 64 + c2 * 8;
  }

  auto STAGE = [&](int set, int kt) {
    f16* base = SM + set * 16384;
    GLL(A + offA0 + kt, base + Ld0);
    GLL(A + offA1 + kt, base + Ld1);
    GLL(B + offB0 + kt, base + 8192 + Ld0);
    GLL(B + offB1 + kt, base + 8192 + Ld1);
  };
  auto COMPUTE = [&](int set) {
    const f16* p = SM + set * 16384;
    half8 a[8], b[4];
    #pragma unroll
    for (int mf = 0; mf < 8; ++mf) a[mf] = *(const half8*)&p[aoff[mf]];
    #pragma unroll
    for (int nf = 0; nf < 4; ++nf) b[nf] = *(const half8*)&p[boff[nf]];
    __builtin_amdgcn_s_setprio(1);
    #pragma unroll
    for (int mf = 0; mf < 8; ++mf)
      #pragma unroll
      for (int nf = 0; nf < 4; ++nf)
        acc[mf][nf] = MFMA16(a[mf], b[nf], acc[mf][nf]);
    __builtin_amdgcn_s_setprio(0);
  };

  STAGE(0, 0);
  STAGE(1, 32);
  #pragma unroll 1
  for (int t = 0; t < NT - 2; ++t) {
    STAGE((t + 2) & 3, (t + 2) * 32);
    WAITN(8);
    __builtin_amdgcn_s_barrier();
    COMPUTE(t & 3);
  }
  WAITN(4);
  __builtin_amdgcn_s_barrier();
  COMPUTE((NT - 2) & 3);
  WAITN(0);
  __builtin_amdgcn_s_barrier();
  COMPUTE((NT - 1) & 3);
}

// ---------------- prep kernels ----------------

__global__ __launch_bounds__(256) void c_kernel(const float* __restrict__ W1,
                                                const float* __restrict__ b1,
                                                const float* __restrict__ hist,
                                                float* __restrict__ c) {
  const int wave = threadIdx.x >> 6, lane = threadIdx.x & 63;
  const int j = blockIdx.x * 4 + wave;
  const float* row = W1 + (size_t)j * 4096;
  float s = 0.f;
  #pragma unroll 2
  for (int kq = lane; kq < 512; kq += 64) {
    const float4 w = *(const float4*)&row[kq * 4];
    const float4 h = *(const float4*)&hist[kq * 4];
    s += w.x * h.x + w.y * h.y + w.z * h.z + w.w * h.w;
  }
  #pragma unroll
  for (int mask = 1; mask < 64; mask <<= 1) s += __shfl_xor(s, mask);
  if (lane == 0) c[j] = s + b1[j];
}

__device__ __forceinline__ half4_t f16hi4(const float4 v) {
  half4_t h;
  h.x = (f16)v.x; h.y = (f16)v.y; h.z = (f16)v.z; h.w = (f16)v.w;
  return h;
}

// blocks 0..4095: A rows (4/block) -> Af + ab2;  blocks 4096..4127: Q -> Qf
__global__ __launch_bounds__(256) void prep_AQ(const float* __restrict__ A,
                                               const float* __restrict__ Q,
                                               const float* __restrict__ b2,
                                               f16* __restrict__ Af,
                                               f16* __restrict__ Qf,
                                               float* __restrict__ ab2) {
  const int wv = threadIdx.x >> 6, lane = threadIdx.x & 63;
  if (blockIdx.x < 4096) {
    const size_t row = (size_t)blockIdx.x * 4 + wv;
    const float* ar = A + row * 2048;
    float dot = 0.f;
    #pragma unroll 2
    for (int c0 = 0; c0 < 2048; c0 += 256) {
      const int col = c0 + lane * 4;
      const float4 v = *(const float4*)&ar[col];
      const float4 bb = *(const float4*)&b2[col];
      dot += v.x * bb.x + v.y * bb.y + v.z * bb.z + v.w * bb.w;
      *(half4_t*)&Af[row * 2048 + col] = f16hi4(v);
    }
    #pragma unroll
    for (int mask = 1; mask < 64; mask <<= 1) dot += __shfl_xor(dot, mask);
    if (lane == 0) ab2[row] = dot;
  } else {
    const size_t row = (size_t)(blockIdx.x - 4096) * 4 + wv;
    const float* qr = Q + row * 2048;
    #pragma unroll 2
    for (int c0 = 0; c0 < 2048; c0 += 256) {
      const int col = c0 + lane * 4;
      const float4 v = *(const float4*)&qr[col];
      *(half4_t*)&Qf[row * 2048 + col] = f16hi4(v);
    }
  }
}

// dst[c*ldR + r] = (f16)src[r*C + c]
__global__ __launch_bounds__(256) void transpose_f16(const float* __restrict__ src,
                                                     int R, int C,
                                                     f16* __restrict__ dst) {
  __shared__ float T[64][65];
  const int c0 = blockIdx.x * 64, r0 = blockIdx.y * 64;
  const int t = threadIdx.x;
  {
    const int rl = t >> 4, cl = (t & 15) * 4;
    #pragma unroll
    for (int ii = 0; ii < 4; ++ii) {
      const float4 v = *(const float4*)&src[(size_t)(r0 + rl + ii * 16) * C + c0 + cl];
      T[rl + ii * 16][cl + 0] = v.x; T[rl + ii * 16][cl + 1] = v.y;
      T[rl + ii * 16][cl + 2] = v.z; T[rl + ii * 16][cl + 3] = v.w;
    }
  }
  __syncthreads();
  const int cc = t >> 2, rr0 = (t & 3) * 16;
  f16 u[16];
  #pragma unroll
  for (int k = 0; k < 16; ++k) u[k] = (f16)T[rr0 + k][cc];
  f16* ph = dst + (size_t)(c0 + cc) * R + r0 + rr0;
  #pragma unroll
  for (int k4 = 0; k4 < 4; ++k4)
    *(half4_t*)&ph[k4 * 4] = *(half4_t*)&u[k4 * 4];
}

// fp32 tiled GEMM (B^T layout), split-K fp32 partial output
template <int BM, int TM>
__global__ __launch_bounds__(256) void gemm_bt_sk(const float* __restrict__ A,
                                                  const float* __restrict__ B,
                                                  float* __restrict__ Cpart,
                                                  int Kslab, int lda, int ldb,
                                                  int ldc, int M) {
  constexpr int BN = 64, BK = 32;
  constexpr int ASTR = BM + 12, BSTR = BN + 4;
  __shared__ float As[BK][ASTR];
  __shared__ float Bs[BK][BSTR];
  const int tid = threadIdx.x;
  const int tx = tid & 15, ty = tid >> 4;
  const int m0 = ty * TM, n0 = tx * 4;
  const size_t bm = (size_t)blockIdx.x * BM, bn = (size_t)blockIdx.y * BN;
  const int kb = blockIdx.z * Kslab;
  const float* Ab = A + bm * lda;
  const float* Bb = B + bn * ldb;
  float acc[TM][4];
  #pragma unroll
  for (int i = 0; i < TM; ++i)
    #pragma unroll
    for (int j = 0; j < 4; ++j) acc[i][j] = 0.f;
  for (int kt = kb; kt < kb + Kslab; kt += BK) {
    #pragma unroll
    for (int it = 0; it < BM * BK / 4 / 256; ++it) {
      const int idx = it * 256 + tid;
      const int row = idx >> 3, kq = idx & 7;
      const float4 v = *(const float4*)&Ab[(size_t)row * lda + kt + kq * 4];
      As[kq * 4 + 0][row] = v.x; As[kq * 4 + 1][row] = v.y;
      As[kq * 4 + 2][row] = v.z; As[kq * 4 + 3][row] = v.w;
    }
    #pragma unroll
    for (int it = 0; it < BN * BK / 4 / 256; ++it) {
      const int idx = it * 256 + tid;
      const int row = idx >> 3, kq = idx & 7;
      const float4 v = *(const float4*)&Bb[(size_t)row * ldb + kt + kq * 4];
      Bs[kq * 4 + 0][row] = v.x; Bs[kq * 4 + 1][row] = v.y;
      Bs[kq * 4 + 2][row] = v.z; Bs[kq * 4 + 3][row] = v.w;
    }
    __syncthreads();
    #pragma unroll
    for (int k = 0; k < BK; ++k) {
      float av[TM];
      #pragma unroll
      for (int i = 0; i < TM; ++i) av[i] = As[k][m0 + i];
      const float4 b = *(const float4*)&Bs[k][n0];
      const float bv[4] = {b.x, b.y, b.z, b.w};
      #pragma unroll
      for (int i = 0; i < TM; ++i)
        #pragma unroll
        for (int j = 0; j < 4; ++j) acc[i][j] = fmaf(av[i], bv[j], acc[i][j]);
    }
    __syncthreads();
  }
  float* base = Cpart + (size_t)blockIdx.z * M * ldc;
  #pragma unroll
  for (int i = 0; i < TM; ++i) {
    float* crow = base + (bm + m0 + i) * (size_t)ldc + bn + n0;
    #pragma unroll
    for (int j = 0; j < 4; ++j) crow[j] = acc[i][j];
  }
}

// QWt[i] = (f16) sum_z part[z][i]
__global__ __launch_bounds__(256) void qwt_combine(const float* __restrict__ part,
                                                   f16* __restrict__ QWt) {
  const size_t i = ((size_t)blockIdx.x * 256 + threadIdx.x) * 4;
  float4 s = make_float4(0.f, 0.f, 0.f, 0.f);
  #pragma unroll
  for (int z = 0; z < 8; ++z) {
    const float4 v = *(const float4*)&part[(size_t)z * 262144 + i];
    s.x += v.x; s.y += v.y; s.z += v.z; s.w += v.w;
  }
  *(half4_t*)&QWt[i] = f16hi4(s);
}

// ------- S partials: Sp[kz][m][n] = Af[m, kz*1024:+1024] @ Qf^T -------
__global__ __launch_bounds__(256, 2) void s_attn_sk(const f16* __restrict__ Af,
                                                    const f16* __restrict__ Qf,
                                                    float* __restrict__ Sp) {
  __shared__ f16 SM[32768];  // 64 KB
  const int tid = threadIdx.x, lane = tid & 63, wv = tid >> 6;
  const int wm = (wv >> 1) * 64, wn = (wv & 1) * 64;
  const int f = lane & 15, kk = lane >> 4;
  const size_t bm = (size_t)(blockIdx.x >> 1) * 128;
  const int kz = blockIdx.x & 1;

  f32x4 acc[4][4];
  #pragma unroll
  for (int mf = 0; mf < 4; ++mf)
    #pragma unroll
    for (int nf = 0; nf < 4; ++nf) acc[mf][nf] = 0.f;

  kloop1<32, 2048, 2048>(Af + bm * 2048 + kz * 1024, Qf + kz * 1024,
                         SM, acc, lane, wv, wm, wn);

  float* out = Sp + (size_t)kz * 16384 * 128;
  #pragma unroll
  for (int mf = 0; mf < 4; ++mf)
    #pragma unroll
    for (int r = 0; r < 4; ++r) {
      const size_t row = bm + wm + mf * 16 + kk * 4 + r;
      #pragma unroll
      for (int nf = 0; nf < 4; ++nf)
        out[row * 128 + wn + nf * 16 + f] = acc[mf][nf][r];
    }
}

// at = (f16) softmax_rows(Sp0 + Sp1).  grid 512 x 256 (8 threads/row).
__global__ __launch_bounds__(256) void softmax_at(const float* __restrict__ Sp,
                                                  f16* __restrict__ at) {
  const int tid = threadIdx.x;
  const int sub = tid & 7;
  const size_t row = (size_t)blockIdx.x * 32 + (tid >> 3);
  const float* p0 = Sp + row * 128 + sub * 16;
  const float* p1 = p0 + (size_t)16384 * 128;
  float v[16];
  #pragma unroll
  for (int q = 0; q < 4; ++q) {
    const float4 a = ((const float4*)p0)[q];
    const float4 b = ((const float4*)p1)[q];
    v[q * 4 + 0] = a.x + b.x; v[q * 4 + 1] = a.y + b.y;
    v[q * 4 + 2] = a.z + b.z; v[q * 4 + 3] = a.w + b.w;
  }
  float mx = v[0];
  #pragma unroll
  for (int e = 1; e < 16; ++e) mx = fmaxf(mx, v[e]);
  mx = fmaxf(mx, __shfl_xor(mx, 1));
  mx = fmaxf(mx, __shfl_xor(mx, 2));
  mx = fmaxf(mx, __shfl_xor(mx, 4));
  float sm = 0.f;
  #pragma unroll
  for (int e = 0; e < 16; ++e) { v[e] = __expf(v[e] - mx); sm += v[e]; }
  sm += __shfl_xor(sm, 1);
  sm += __shfl_xor(sm, 2);
  sm += __shfl_xor(sm, 4);
  const float inv = 1.0f / sm;
  f16* po = at + row * 128 + sub * 16;
  #pragma unroll
  for (int q = 0; q < 4; ++q) {
    half4_t h;
    h.x = (f16)(v[q * 4 + 0] * inv); h.y = (f16)(v[q * 4 + 1] * inv);
    h.z = (f16)(v[q * 4 + 2] * inv); h.w = (f16)(v[q * 4 + 3] * inv);
    *(half4_t*)&po[q * 4] = h;
  }
}

// ---------------- H = relu(at @ QWt + c), 128x128 tile, K=128 ----------------
__global__ __launch_bounds__(256, 2) void h_kernel(const f16* __restrict__ at,
                                                   const f16* __restrict__ QWt,
                                                   const float* __restrict__ cvec,
                                                   f16* __restrict__ H) {
  __shared__ f16 SM[32768];  // 64 KB
  const int tid = threadIdx.x, lane = tid & 63, wv = tid >> 6;
  const int wm = (wv >> 1) * 64, wn = (wv & 1) * 64;
  const int f = lane & 15, kk = lane >> 4;
  const size_t bm = (size_t)(blockIdx.x & 127) * 128;
  const size_t bn = (size_t)(blockIdx.x >> 7) * 128;

  f32x4 acc[4][4];
  #pragma unroll
  for (int mf = 0; mf < 4; ++mf)
    #pragma unroll
    for (int nf = 0; nf < 4; ++nf) acc[mf][nf] = 0.f;

  kloop1<4, 128, 128>(at + bm * 128, QWt + bn * 128, SM, acc, lane, wv, wm, wn);

  float ccv[4];
  #pragma unroll
  for (int nf = 0; nf < 4; ++nf) ccv[nf] = cvec[bn + wn + nf * 16 + f];

  __syncthreads();
  constexpr int STR = 136;
  f16* T = SM;
  #pragma unroll
  for (int mf = 0; mf < 4; ++mf)
    #pragma unroll
    for (int r = 0; r < 4; ++r) {
      const int row = wm + mf * 16 + kk * 4 + r;
      #pragma unroll
      for (int nf = 0; nf < 4; ++nf)
        T[row * STR + wn + nf * 16 + f] =
            (f16)fmaxf(acc[mf][nf][r] + ccv[nf], 0.f);
    }
  __syncthreads();
  #pragma unroll
  for (int it = 0; it < 8; ++it) {
    const int row = it * 16 + (tid >> 4);
    const int ch = tid & 15;
    const float4 vv = *(const float4*)&T[row * STR + ch * 8];
    *(float4*)&H[(bm + row) * 2048 + bn + ch * 8] = vv;
  }
}

// --- fused G: G = Af @ W2t (256x256 tile) + dot with H (R11 proven) ---
__global__ __launch_bounds__(512, 1) void fused_g(
    const f16* __restrict__ Af, const f16* __restrict__ H,
    const f16* __restrict__ W2t, float* __restrict__ partial) {
  extern __shared__ f16 SM[];  // 128 KB: 4 sets x {A 16KB, B 16KB}
  const int tid = threadIdx.x, lane = tid & 63, wv = tid >> 6;   // wv 0..7
  const int wm = (wv >> 2) * 128, wn = (wv & 3) * 64;
  const int f = lane & 15, kk = lane >> 4;
  // bijective XCD swizzle: nwg=512, 8 XCDs, 64 per XCD
  const int lin = blockIdx.x;
  const int sid = (lin & 7) * 64 + (lin >> 3);
  const int bmI = sid & 63, bnI = sid >> 6;       // 64 m-blocks x 8 n-blocks
  const size_t bm = (size_t)bmI * 256;
  const size_t bn = (size_t)bnI * 256;

  f32x4 acc[8][4];
  #pragma unroll
  for (int mf = 0; mf < 8; ++mf)
    #pragma unroll
    for (int nf = 0; nf < 4; ++nf) acc[mf][nf] = 0.f;

  kloop256<64, 2048, 2048>(Af + bm * 2048, W2t + bn * 2048, SM, acc, lane, wv, wm, wn);

  // epilogue: load H frags from global, dot, reduce over 16-lane groups
  float part[8][4];
  #pragma unroll
  for (int mf = 0; mf < 8; ++mf)
    #pragma unroll
    for (int r = 0; r < 4; ++r) {
      const size_t hrow = (bm + wm + mf * 16 + kk * 4 + r) * 2048 + bn + wn + f;
      float s = 0.f;
      #pragma unroll
      for (int nf = 0; nf < 4; ++nf)
        s += (float)H[hrow + nf * 16] * acc[mf][nf][r];
      part[mf][r] = s;
    }
  #pragma unroll
  for (int mf = 0; mf < 8; ++mf)
    #pragma unroll
    for (int r = 0; r < 4; ++r) {
      part[mf][r] += __shfl_xor(part[mf][r], 1);
      part[mf][r] += __shfl_xor(part[mf][r], 2);
      part[mf][r] += __shfl_xor(part[mf][r], 4);
      part[mf][r] += __shfl_xor(part[mf][r], 8);
    }
  if (f == 0) {
    const size_t slab = (size_t)(bnI * 4 + (wv & 3)) * 16384;
    #pragma unroll
    for (int mf = 0; mf < 8; ++mf)
      #pragma unroll
      for (int r = 0; r < 4; ++r)
        partial[slab + bm + wm + mf * 16 + kk * 4 + r] = part[mf][r];
  }
}

// ---------------- final reduction + softmax over M ----------------

__global__ __launch_bounds__(256) void k_sem(const float* __restrict__ partial,
                                             const float* __restrict__ ab2,
                                             float* __restrict__ semantic,
                                             float* __restrict__ bstats) {
  const int m = blockIdx.x * 256 + threadIdx.x;
  float s = ab2[m];
  #pragma unroll
  for (int nb = 0; nb < 32; ++nb) s += partial[(size_t)nb * 16384 + m];
  semantic[m] = s;
  float mx = s;
  #pragma unroll
  for (int mask = 1; mask < 64; mask <<= 1) mx = fmaxf(mx, __shfl_xor(mx, mask));
  __shared__ float wmax[4], wsum[4];
  const int wave = threadIdx.x >> 6, lane = threadIdx.x & 63;
  if (lane == 0) wmax[wave] = mx;
  __syncthreads();
  const float bmax = fmaxf(fmaxf(wmax[0], wmax[1]), fmaxf(wmax[2], wmax[3]));
  float e = expf(s - bmax);
  #pragma unroll
  for (int mask = 1; mask < 64; mask <<= 1) e += __shfl_xor(e, mask);
  if (lane == 0) wsum[wave] = e;
  __syncthreads();
  if (threadIdx.x == 0) {
    bstats[blockIdx.x * 2] = bmax;
    bstats[blockIdx.x * 2 + 1] = wsum[0] + wsum[1] + wsum[2] + wsum[3];
  }
}

__global__ __launch_bounds__(256) void k_out(const float* __restrict__ semantic,
                                             const float* __restrict__ bstats,
                                             float* __restrict__ out) {
  __shared__ float g0s, g1s;
  const int tid = threadIdx.x;
  if (tid < 64) {
    const float bm = bstats[tid * 2], bs = bstats[tid * 2 + 1];
    float gm = bm;
    #pragma unroll
    for (int mask = 1; mask < 64; mask <<= 1) gm = fmaxf(gm, __shfl_xor(gm, mask));
    float gs = bs * expf(bm - gm);
    #pragma unroll
    for (int mask = 1; mask < 64; mask <<= 1) gs += __shfl_xor(gs, mask);
    if (tid == 0) { g0s = gm; g1s = gs; }
  }
  __syncthreads();
  const int m = blockIdx.x * 256 + tid;
  out[m] = expf(semantic[m] - g0s) / g1s;
}

// ---------------- launch ----------------

extern "C" void kernel_launch(void* const* d_in, const int* in_sizes, int n_in,
                              void* d_out, int out_size, void* d_ws, size_t ws_size,
                              hipStream_t stream) {
  (void)in_sizes; (void)n_in; (void)out_size; (void)ws_size;
  const float* A    = (const float*)d_in[0];  // [16384][2048]
  const float* Q    = (const float*)d_in[1];  // [128][2048]
  const float* hist = (const float*)d_in[2];  // [2048]
  const float* W1   = (const float*)d_in[3];  // [2048][4096]
  const float* b1   = (const float*)d_in[4];  // [2048]
  const float* W2   = (const float*)d_in[5];  // [2048][2048]
  const float* b2   = (const float*)d_in[6];  // [2048]
  float* out = (float*)d_out;                 // [16384]

  char* ws = (char*)d_ws;
  f16* Af      = (f16*)ws;   ws += (size_t)16384 * 2048 * 2;  // 64 MB
  f16* Hbuf    = (f16*)ws;   ws += (size_t)16384 * 2048 * 2;  // 64 MB
  f16* W2t     = (f16*)ws;   ws += (size_t)2048 * 2048 * 2;   // 8 MB
  f16* Qf      = (f16*)ws;   ws += (size_t)128 * 2048 * 2;
  f16* QWt     = (f16*)ws;   ws += (size_t)2048 * 128 * 2;
  f16* at      = (f16*)ws;   ws += (size_t)16384 * 128 * 2;   // 4 MB
  float* qwt_part = (float*)ws; ws += (size_t)8 * 2048 * 128 * 4;  // 8 MB
  float* Sp    = (float*)ws; ws += (size_t)2 * 16384 * 128 * 4;    // 16 MB
  float* c_vec = (float*)ws; ws += 2048 * 4;
  float* ab2   = (float*)ws; ws += 16384 * 4;
  float* partial  = (float*)ws; ws += (size_t)32 * 16384 * 4; // 2 MB
  float* semantic = (float*)ws; ws += 16384 * 4;
  float* bstats   = (float*)ws; ws += 128 * 4;

  hipFuncSetAttribute((const void*)fused_g,
                      hipFuncAttributeMaxDynamicSharedMemorySize, 131072);

  // prep
  c_kernel<<<512, 256, 0, stream>>>(W1, b1, hist, c_vec);
  gemm_bt_sk<32, 2><<<dim3(64, 2, 8), 256, 0, stream>>>(W1 + 2048, Q, qwt_part,
                                                        256, 4096, 2048, 128, 2048);
  qwt_combine<<<256, 256, 0, stream>>>(qwt_part, QWt);
  transpose_f16<<<dim3(32, 32), 256, 0, stream>>>(W2, 2048, 2048, W2t);
  prep_AQ<<<4128, 256, 0, stream>>>(A, Q, b2, Af, Qf, ab2);
  // S partials (split-K 2, full GPU) + softmax
  s_attn_sk<<<256, 256, 0, stream>>>(Af, Qf, Sp);
  softmax_at<<<512, 256, 0, stream>>>(Sp, at);
  // H = relu(at@QWt + c), coalesced writes
  h_kernel<<<2048, 256, 0, stream>>>(at, QWt, c_vec, Hbuf);
  // G = Af@W2t + dot with H (256x256 tile, R11 schedule)
  fused_g<<<512, 512, 131072, stream>>>(Af, Hbuf, W2t, partial);
  // semantic + softmax over M
  k_sem<<<64, 256, 0, stream>>>(partial, ab2, semantic, bstats);
  k_out<<<64, 256, 0, stream>>>(semantic, bstats, out);
}